// Round 4
// baseline (396.303 us; speedup 1.0000x reference)
//
#include <hip/hip_runtime.h>
#include <cstdint>
#include <cstddef>

typedef __attribute__((ext_vector_type(8))) short short8;
typedef __attribute__((ext_vector_type(4))) float floatx4;

__device__ __forceinline__ unsigned short f2bf(float f) {
    unsigned int u = __builtin_bit_cast(unsigned int, f);
    u += 0x7fffu + ((u >> 16) & 1u);
    return (unsigned short)(u >> 16);
}
__device__ __forceinline__ short8 pack8(float4 a, float4 b) {
    short8 r;
    r[0] = (short)f2bf(a.x); r[1] = (short)f2bf(a.y);
    r[2] = (short)f2bf(a.z); r[3] = (short)f2bf(a.w);
    r[4] = (short)f2bf(b.x); r[5] = (short)f2bf(b.y);
    r[6] = (short)f2bf(b.z); r[7] = (short)f2bf(b.w);
    return r;
}

// ---------------------------------------------------------------------------
// wave_gemm: ONE WAVE per block, tile 64(M) x 32(N), NO LDS, NO BARRIERS.
// Round-3 lesson: the 2-deep register pipeline exceeds the 96-VGPR budget,
// so the compiler serializes loads anyway -> each K-step pays full HBM
// latency. Fix is TLP, not ILP: split K so every wave is a uniform short
// job and the grid is >=18 waves/CU (96 VGPR allows 5 waves/SIMD).
// mode 0 (NT): W f32 (N,K) row-major, k contiguous  (qheads/inproj/outproj)
// mode 1 (NN): W f32 (K,N) k-major, ldw = row stride (lifts)
// Split-K via atomicAdd when nkz>1 (dest pre-zeroed); bias added at kz==0.
// ---------------------------------------------------------------------------
struct WaveG {
    const float* A; const float* W; const float* bias; float* C;
    int K, Kc, ldw, ldc, nj, nkz, mode;
};
struct WaveBatch { WaveG d[16]; int start[16]; int nd; };

#define MFMA_ALL() { _Pragma("unroll") for (int r_ = 0; r_ < 4; ++r_) { \
    acc[r_][0] = __builtin_amdgcn_mfma_f32_16x16x32_bf16(af[r_], bfr0, acc[r_][0], 0, 0, 0); \
    acc[r_][1] = __builtin_amdgcn_mfma_f32_16x16x32_bf16(af[r_], bfr1, acc[r_][1], 0, 0, 0); } }

#define LOADA(dst) { _Pragma("unroll") for (int r_ = 0; r_ < 4; ++r_) { \
    dst[r_][0] = *(const float4*)pa[r_]; dst[r_][1] = *(const float4*)(pa[r_] + 4); \
    pa[r_] += 32; } }

#define PACKA(src) { _Pragma("unroll") for (int r_ = 0; r_ < 4; ++r_) \
    af[r_] = pack8(src[r_][0], src[r_][1]); }

__global__ __launch_bounds__(64) void wave_gemm(WaveBatch wb)
{
    const int bx = blockIdx.x;
    int di = 0;
#pragma unroll 1
    for (int i = 1; i < wb.nd; ++i) if (bx >= wb.start[i]) di = i;
    const WaveG g = wb.d[di];
    int local = bx - wb.start[di];
    const int j = local % g.nj;
    const int kz = local / g.nj;

    const int lane = threadIdx.x;
    const int quad = lane >> 4, l16 = lane & 15;

    const float* pa[4];
#pragma unroll
    for (int r = 0; r < 4; ++r)
        pa[r] = g.A + (size_t)(r * 16 + l16) * g.K + kz * g.Kc + quad * 8;

    floatx4 acc[4][2] = {};
    const int steps = g.Kc >> 5;   // even for all uses
    short8 af[4], bfr0, bfr1;

    if (g.mode == 0) {
        const float* pb0 = g.W + (size_t)(j * 32 + l16) * g.K + kz * g.Kc + quad * 8;
        const float* pb1 = pb0 + (size_t)16 * g.K;
        float4 xa[4][2], ya[4][2];
        float4 xb[2][2], yb[2][2];
#define LOADB_NT(dst) { dst[0][0] = *(const float4*)pb0; dst[0][1] = *(const float4*)(pb0 + 4); \
        dst[1][0] = *(const float4*)pb1; dst[1][1] = *(const float4*)(pb1 + 4); \
        pb0 += 32; pb1 += 32; }
        LOADA(xa); LOADB_NT(xb);
        LOADA(ya); LOADB_NT(yb);
#pragma unroll 1
        for (int s = 0; s < steps; s += 2) {
            PACKA(xa);
            bfr0 = pack8(xb[0][0], xb[0][1]); bfr1 = pack8(xb[1][0], xb[1][1]);
            MFMA_ALL();
            if (s + 2 < steps) { LOADA(xa); LOADB_NT(xb); }
            PACKA(ya);
            bfr0 = pack8(yb[0][0], yb[0][1]); bfr1 = pack8(yb[1][0], yb[1][1]);
            MFMA_ALL();
            if (s + 3 < steps) { LOADA(ya); LOADB_NT(yb); }
        }
    } else {
        const float* pw[8];
#pragma unroll
        for (int i = 0; i < 8; ++i)
            pw[i] = g.W + ((size_t)(kz * g.Kc) + quad * 8 + i) * g.ldw + j * 32 + l16;
        const size_t ldw32 = (size_t)32 * g.ldw;
        float4 xa[4][2], ya[4][2];
        float xb[16], yb[16];
#define LOADB_NN(dst) { _Pragma("unroll") for (int i_ = 0; i_ < 8; ++i_) { \
        dst[i_] = pw[i_][0]; dst[8 + i_] = pw[i_][16]; pw[i_] += ldw32; } }
#define CVTB(src) { _Pragma("unroll") for (int e_ = 0; e_ < 8; ++e_) { \
        bfr0[e_] = (short)f2bf(src[e_]); bfr1[e_] = (short)f2bf(src[8 + e_]); } }
        LOADA(xa); LOADB_NN(xb);
        LOADA(ya); LOADB_NN(yb);
#pragma unroll 1
        for (int s = 0; s < steps; s += 2) {
            PACKA(xa);
            CVTB(xb);
            MFMA_ALL();
            if (s + 2 < steps) { LOADA(xa); LOADB_NN(xb); }
            PACKA(ya);
            CVTB(yb);
            MFMA_ALL();
            if (s + 3 < steps) { LOADA(ya); LOADB_NN(yb); }
        }
    }

#pragma unroll
    for (int r = 0; r < 4; ++r)
#pragma unroll
        for (int c = 0; c < 2; ++c) {
            const int col = j * 32 + c * 16 + l16;
            const float bj = (kz == 0) ? g.bias[col] : 0.f;
#pragma unroll
            for (int q = 0; q < 4; ++q) {
                const int row = r * 16 + quad * 4 + q;
                const float v = acc[r][c][q] + bj;
                if (g.nkz > 1) atomicAdd(&g.C[(size_t)row * g.ldc + col], v);
                else           g.C[(size_t)row * g.ldc + col] = v;
            }
        }
}

// ---------------------------------------------------------------------------
// gemm128: 128x128x32 tile for the big kv projections (NT, W f32 (N,K),
// bf16 out). 4 waves in 2x2, each 64x64 (acc 4x4). Both operands staged in
// LDS, double-buffered, one barrier per K-step, XOR swizzle (2-way, free).
// ---------------------------------------------------------------------------
struct Sub128 { const float* A; const float* W; const float* bias; unsigned short* C; int K, N, nj; };
struct Batch128 { Sub128 d[4]; int start[4]; int nd; };

__global__ __launch_bounds__(256) void gemm128(Batch128 gb)
{
    __shared__ short As[2][128 * 40];
    __shared__ short Bs[2][128 * 40];

    const int bx = blockIdx.x;
    int di = 0;
#pragma unroll 1
    for (int i = 1; i < gb.nd; ++i) if (bx >= gb.start[i]) di = i;
    const Sub128 g = gb.d[di];
    const int local = bx - gb.start[di];
    const int jb = local % g.nj, ib = local / g.nj;

    const int tid = threadIdx.x;
    const int w = tid >> 6, lane = tid & 63;
    const int quad = lane >> 4, l16 = lane & 15;
    const int wm = (w >> 1) * 64, wn = (w & 1) * 64;

    const int rS = tid >> 1;
    const int gi0 = (tid & 1) * 2;
    const int jsw = (rS >> 3) & 3;
    const int s1 = rS * 40 + ((gi0 ^ jsw) << 3);
    const int s2 = rS * 40 + (((gi0 + 1) ^ jsw) << 3);
    const float* pa = g.A + (size_t)(ib * 128 + rS) * g.K + (tid & 1) * 16;
    const float* pb = g.W + (size_t)(jb * 128 + rS) * g.K + (tid & 1) * 16;

    int aoff[4], boff[4];
#pragma unroll
    for (int r = 0; r < 4; ++r) {
        int rowA = wm + r * 16 + l16;
        aoff[r] = rowA * 40 + ((quad ^ ((rowA >> 3) & 3)) << 3);
        int rowB = wn + r * 16 + l16;
        boff[r] = rowB * 40 + ((quad ^ ((rowB >> 3) & 3)) << 3);
    }

    floatx4 acc[4][4] = {};
    float4 a0 = *(const float4*)pa,       a1 = *(const float4*)(pa + 4);
    float4 a2 = *(const float4*)(pa + 8), a3 = *(const float4*)(pa + 12);
    float4 b0 = *(const float4*)pb,       b1 = *(const float4*)(pb + 4);
    float4 b2 = *(const float4*)(pb + 8), b3 = *(const float4*)(pb + 12);
    *(short8*)&As[0][s1] = pack8(a0, a1);
    *(short8*)&As[0][s2] = pack8(a2, a3);
    *(short8*)&Bs[0][s1] = pack8(b0, b1);
    *(short8*)&Bs[0][s2] = pack8(b2, b3);
    if (g.K > 32) {
        pa += 32; pb += 32;
        a0 = *(const float4*)pa;       a1 = *(const float4*)(pa + 4);
        a2 = *(const float4*)(pa + 8); a3 = *(const float4*)(pa + 12);
        b0 = *(const float4*)pb;       b1 = *(const float4*)(pb + 4);
        b2 = *(const float4*)(pb + 8); b3 = *(const float4*)(pb + 12);
    }
    int cur = 0;
#pragma unroll 1
    for (int k0 = 0; k0 < g.K; k0 += 32) {
        __syncthreads();
        short8 af[4], bf[4];
#pragma unroll
        for (int r = 0; r < 4; ++r) {
            af[r] = *(const short8*)&As[cur][aoff[r]];
            bf[r] = *(const short8*)&Bs[cur][boff[r]];
        }
#pragma unroll
        for (int r = 0; r < 4; ++r)
#pragma unroll
            for (int c = 0; c < 4; ++c)
                acc[r][c] = __builtin_amdgcn_mfma_f32_16x16x32_bf16(af[r], bf[c], acc[r][c], 0, 0, 0);
        if (k0 + 32 < g.K) {
            short* An = As[cur ^ 1]; short* Bn = Bs[cur ^ 1];
            *(short8*)&An[s1] = pack8(a0, a1);
            *(short8*)&An[s2] = pack8(a2, a3);
            *(short8*)&Bn[s1] = pack8(b0, b1);
            *(short8*)&Bn[s2] = pack8(b2, b3);
            if (k0 + 64 < g.K) {
                pa += 32; pb += 32;
                a0 = *(const float4*)pa;       a1 = *(const float4*)(pa + 4);
                a2 = *(const float4*)(pa + 8); a3 = *(const float4*)(pa + 12);
                b0 = *(const float4*)pb;       b1 = *(const float4*)(pb + 4);
                b2 = *(const float4*)(pb + 8); b3 = *(const float4*)(pb + 12);
            }
        }
        cur ^= 1;
    }

#pragma unroll
    for (int r = 0; r < 4; ++r)
#pragma unroll
        for (int c = 0; c < 4; ++c) {
            const int col = jb * 128 + wn + c * 16 + l16;
            const float bj = g.bias[col];
#pragma unroll
            for (int q = 0; q < 4; ++q) {
                const int row = ib * 128 + wm + r * 16 + quad * 4 + q;
                g.C[(size_t)row * g.N + col] = f2bf(acc[r][c][q] + bj);
            }
        }
}

// ---------------------------------------------------------------------------
// qk_batch: S(64b x 128m tile) = 0.125 * Q_h @ K_h^T, all 28 heads batched.
// ---------------------------------------------------------------------------
__global__ __launch_bounds__(256) void qk_batch(
    const float* __restrict__ qp_t, const float* __restrict__ qp_p, const float* __restrict__ qp_c,
    const unsigned short* __restrict__ kv_t, const unsigned short* __restrict__ kv_p, const unsigned short* __restrict__ kv_c,
    float* __restrict__ S_t, float* __restrict__ S_p, float* __restrict__ S_c)
{
    __shared__ short As[64 * 72];
    __shared__ short Bs[128 * 72];
    const int hy = blockIdx.y;
    const float* qp; const unsigned short* kv; float* S; int d, h;
    if (hy < 4)       { qp = qp_t; kv = kv_t; S = S_t; d = 256;  h = hy; }
    else if (hy < 12) { qp = qp_p; kv = kv_p; S = S_p; d = 512;  h = hy - 4; }
    else              { qp = qp_c; kv = kv_c; S = S_c; d = 1024; h = hy - 12; }

    const int j0 = blockIdx.x * 128;
    const int tid = threadIdx.x;
    const int w = tid >> 6, lane = tid & 63;
    const int quad = lane >> 4, l16 = lane & 15;
    const int noff = w * 32;
    const int twoD = 2 * d;

    {
        const int b = tid >> 2, kc = (tid & 3) * 16;
        const float* ga = qp + (size_t)b * d + h * 64 + kc;
        float4 a0 = *(const float4*)(ga + 0), a1 = *(const float4*)(ga + 4);
        float4 a2 = *(const float4*)(ga + 8), a3 = *(const float4*)(ga + 12);
        *(short8*)&As[b * 72 + kc + 0] = pack8(a0, a1);
        *(short8*)&As[b * 72 + kc + 8] = pack8(a2, a3);
    }
    {
        const int m = tid >> 1, hf = (tid & 1) * 32;
        const unsigned short* gb = kv + (size_t)(j0 + m) * twoD + h * 64 + hf;
        uint4 b0 = *(const uint4*)(gb + 0),  b1 = *(const uint4*)(gb + 8);
        uint4 b2 = *(const uint4*)(gb + 16), b3 = *(const uint4*)(gb + 24);
        *(uint4*)&Bs[m * 72 + hf + 0]  = b0;
        *(uint4*)&Bs[m * 72 + hf + 8]  = b1;
        *(uint4*)&Bs[m * 72 + hf + 16] = b2;
        *(uint4*)&Bs[m * 72 + hf + 24] = b3;
    }
    __syncthreads();

    floatx4 acc[4][2] = {};
#pragma unroll
    for (int k0 = 0; k0 < 64; k0 += 32) {
        short8 af[4], bfr[2];
#pragma unroll
        for (int r = 0; r < 4; ++r)
            af[r] = *(const short8*)&As[(r * 16 + l16) * 72 + k0 + quad * 8];
#pragma unroll
        for (int c = 0; c < 2; ++c)
            bfr[c] = *(const short8*)&Bs[(noff + c * 16 + l16) * 72 + k0 + quad * 8];
#pragma unroll
        for (int r = 0; r < 4; ++r)
#pragma unroll
            for (int c = 0; c < 2; ++c)
                acc[r][c] = __builtin_amdgcn_mfma_f32_16x16x32_bf16(af[r], bfr[c], acc[r][c], 0, 0, 0);
    }
#pragma unroll
    for (int r = 0; r < 4; ++r)
#pragma unroll
        for (int c = 0; c < 2; ++c) {
            int col = j0 + noff + c * 16 + l16;
#pragma unroll
            for (int q = 0; q < 4; ++q) {
                int row = r * 16 + quad * 4 + q;
                S[((size_t)h * 64 + row) * 2048 + col] = acc[r][c][q] * 0.125f;
            }
        }
}

// ---------------------------------------------------------------------------
// softmax_p: per (head, b): softmax over the S row, written back IN PLACE.
// ---------------------------------------------------------------------------
__global__ __launch_bounds__(256) void softmax_p(
    float* __restrict__ S_t, float* __restrict__ S_p, float* __restrict__ S_c,
    const uint8_t* __restrict__ mask)
{
    const int hy = blockIdx.x, b = blockIdx.y;
    float* S; int h;
    if (hy < 4)       { S = S_t; h = hy; }
    else if (hy < 12) { S = S_p; h = hy - 4; }
    else              { S = S_c; h = hy - 12; }

    const int tid = threadIdx.x;
    __shared__ __align__(16) float sc[2048];
    __shared__ float red[4];
    __shared__ float s_max, s_sum;

    float* Sr = S + ((size_t)h * 64 + b) * 2048;
    const uint8_t* mr = mask + (size_t)b * 2048;

    float lmax = -1e30f;
    for (int m = tid; m < 2048; m += 256) {
        float s = Sr[m];
        if (mr[m]) s = -1e9f;
        sc[m] = s;
        lmax = fmaxf(lmax, s);
    }
#pragma unroll
    for (int off = 32; off; off >>= 1) lmax = fmaxf(lmax, __shfl_down(lmax, off));
    if ((tid & 63) == 0) red[tid >> 6] = lmax;
    __syncthreads();
    if (tid == 0) s_max = fmaxf(fmaxf(red[0], red[1]), fmaxf(red[2], red[3]));
    __syncthreads();
    const float mx = s_max;

    float lsum = 0.f;
    for (int m = tid; m < 2048; m += 256) {
        float e = __expf(sc[m] - mx);
        sc[m] = e;
        lsum += e;
    }
#pragma unroll
    for (int off = 32; off; off >>= 1) lsum += __shfl_down(lsum, off);
    if ((tid & 63) == 0) red[tid >> 6] = lsum;
    __syncthreads();
    if (tid == 0) s_sum = red[0] + red[1] + red[2] + red[3];
    __syncthreads();
    const float inv = 1.f / s_sum;

    for (int m = tid; m < 2048; m += 256) Sr[m] = sc[m] * inv;
}

// ---------------------------------------------------------------------------
// pv_batch: O_h = P_h(64x2048) @ V_h(2048x64), one wave per (head, k-chunk
// of 128). Grid (28, 16). atomicAdd into zeroed o_*.
// ---------------------------------------------------------------------------
__global__ __launch_bounds__(64) void pv_batch(
    const float* __restrict__ P_t, const float* __restrict__ P_p, const float* __restrict__ P_c,
    const unsigned short* __restrict__ kv_t, const unsigned short* __restrict__ kv_p, const unsigned short* __restrict__ kv_c,
    float* __restrict__ o_t, float* __restrict__ o_p, float* __restrict__ o_c)
{
    const int hy = blockIdx.x, kz = blockIdx.y;
    const float* P; const unsigned short* kv; float* o; int d, h;
    if (hy < 4)       { P = P_t; kv = kv_t; o = o_t; d = 256;  h = hy; }
    else if (hy < 12) { P = P_p; kv = kv_p; o = o_p; d = 512;  h = hy - 4; }
    else              { P = P_c; kv = kv_c; o = o_c; d = 1024; h = hy - 12; }

    const int lane = threadIdx.x;
    const int quad = lane >> 4, l16 = lane & 15;
    const int twoD = 2 * d;

    const float* pa[4];
#pragma unroll
    for (int r = 0; r < 4; ++r)
        pa[r] = P + ((size_t)h * 64 + r * 16 + l16) * 2048 + kz * 128 + quad * 8;
    const unsigned short* pb = kv + (size_t)(kz * 128 + quad * 8) * twoD + d + h * 64 + l16;

    floatx4 acc[4][4] = {};
#pragma unroll 1
    for (int s = 0; s < 4; ++s) {
        short8 af[4];
#pragma unroll
        for (int r = 0; r < 4; ++r) {
            float4 a0 = *(const float4*)pa[r], a1 = *(const float4*)(pa[r] + 4);
            af[r] = pack8(a0, a1);
            pa[r] += 32;
        }
        short8 bf[4];
#pragma unroll
        for (int c = 0; c < 4; ++c)
#pragma unroll
            for (int i = 0; i < 8; ++i)
                bf[c][i] = (short)pb[(size_t)i * twoD + c * 16];
        pb += (size_t)32 * twoD;
#pragma unroll
        for (int r = 0; r < 4; ++r)
#pragma unroll
            for (int c = 0; c < 4; ++c)
                acc[r][c] = __builtin_amdgcn_mfma_f32_16x16x32_bf16(af[r], bf[c], acc[r][c], 0, 0, 0);
    }
#pragma unroll
    for (int r = 0; r < 4; ++r)
#pragma unroll
        for (int c = 0; c < 4; ++c)
#pragma unroll
            for (int q = 0; q < 4; ++q) {
                const int row = r * 16 + quad * 4 + q;
                atomicAdd(&o[(size_t)row * d + h * 64 + c * 16 + l16], acc[r][c][q]);
            }
}

// ---------------------------------------------------------------------------
__global__ __launch_bounds__(256) void ln_kernel(
    float* __restrict__ x, const float* __restrict__ g, const float* __restrict__ bb)
{
    const int row = blockIdx.x;
    float* xr = x + (size_t)row * 4096;
    const int tid = threadIdx.x;
    float v[16];
    float sum = 0.f, sumsq = 0.f;
#pragma unroll
    for (int i = 0; i < 16; ++i) {
        v[i] = xr[tid + i * 256];
        sum += v[i];
        sumsq += v[i] * v[i];
    }
    __shared__ float rs[4], rq[4];
#pragma unroll
    for (int off = 32; off; off >>= 1) {
        sum += __shfl_down(sum, off);
        sumsq += __shfl_down(sumsq, off);
    }
    if ((tid & 63) == 0) { rs[tid >> 6] = sum; rq[tid >> 6] = sumsq; }
    __syncthreads();
    const float ts = rs[0] + rs[1] + rs[2] + rs[3];
    const float tq = rq[0] + rq[1] + rq[2] + rq[3];
    const float mu = ts * (1.f / 4096.f);
    const float var = tq * (1.f / 4096.f) - mu * mu;
    const float r = rsqrtf(var + 1e-5f);
#pragma unroll
    for (int i = 0; i < 16; ++i) {
        int e = tid + i * 256;
        xr[e] = (v[i] - mu) * r * g[e] + bb[e];
    }
}

// ---------------------------------------------------------------------------
static void addw(WaveBatch& G, int& tot,
                 const float* A, const float* W, const float* bias, float* C,
                 int K, int Kc, int ldw, int ldc, int nj, int nkz, int mode)
{
    WaveG& s = G.d[G.nd];
    s.A = A; s.W = W; s.bias = bias; s.C = C;
    s.K = K; s.Kc = Kc; s.ldw = ldw; s.ldc = ldc; s.nj = nj; s.nkz = nkz; s.mode = mode;
    G.start[G.nd] = tot;
    tot += nj * nkz;
    G.nd++;
}
static void add128(Batch128& G, int& tot,
                   const float* A, const float* W, const float* bias, unsigned short* C,
                   int K, int N, int nj, int ni)
{
    Sub128& s = G.d[G.nd];
    s.A = A; s.W = W; s.bias = bias; s.C = C; s.K = K; s.N = N; s.nj = nj;
    G.start[G.nd] = tot;
    tot += nj * ni;
    G.nd++;
}

extern "C" void kernel_launch(void* const* d_in, const int* in_sizes, int n_in,
                              void* d_out, int out_size, void* d_ws, size_t ws_size,
                              hipStream_t stream)
{
    const float*   hs     = (const float*)d_in[0];
    const float*   fib_t  = (const float*)d_in[1];
    const float*   fib_p  = (const float*)d_in[2];
    const float*   fib_c  = (const float*)d_in[3];
    const uint8_t* mask   = (const uint8_t*)d_in[4];
    const float* Wq_t   = (const float*)d_in[5];  const float* bq_t   = (const float*)d_in[6];
    const float* Wq_p   = (const float*)d_in[7];  const float* bq_p   = (const float*)d_in[8];
    const float* Wq_c   = (const float*)d_in[9];  const float* bq_c   = (const float*)d_in[10];
    const float* Wqkv_t = (const float*)d_in[11]; const float* bqkv_t = (const float*)d_in[12];
    const float* Wo_t   = (const float*)d_in[13]; const float* bo_t   = (const float*)d_in[14];
    const float* Wqkv_p = (const float*)d_in[15]; const float* bqkv_p = (const float*)d_in[16];
    const float* Wo_p   = (const float*)d_in[17]; const float* bo_p   = (const float*)d_in[18];
    const float* Wqkv_c = (const float*)d_in[19]; const float* bqkv_c = (const float*)d_in[20];
    const float* Wo_c   = (const float*)d_in[21]; const float* bo_c   = (const float*)d_in[22];
    const float* Wl_t   = (const float*)d_in[23]; const float* bl_t   = (const float*)d_in[24];
    const float* Wl_p   = (const float*)d_in[25]; const float* bl_p   = (const float*)d_in[26];
    const float* Wl_c   = (const float*)d_in[27]; const float* bl_c   = (const float*)d_in[28];
    const float* ln_g   = (const float*)d_in[29]; const float* ln_b   = (const float*)d_in[30];

    char* wsb = (char*)d_ws;
    // zeroed region: split-K atomic destinations
    float* q_t  = (float*)wsb; wsb += 64 * 256 * 4;
    float* q_p  = (float*)wsb; wsb += 64 * 512 * 4;
    float* q_c  = (float*)wsb; wsb += 64 * 1024 * 4;
    float* qp_t = (float*)wsb; wsb += 64 * 256 * 4;
    float* qp_p = (float*)wsb; wsb += 64 * 512 * 4;
    float* qp_c = (float*)wsb; wsb += 64 * 1024 * 4;
    float* po_t = (float*)wsb; wsb += 64 * 256 * 4;
    float* po_p = (float*)wsb; wsb += 64 * 512 * 4;
    float* po_c = (float*)wsb; wsb += 64 * 1024 * 4;
    float* o_t  = (float*)wsb; wsb += 64 * 256 * 4;
    float* o_p  = (float*)wsb; wsb += 64 * 512 * 4;
    float* o_c  = (float*)wsb; wsb += 64 * 1024 * 4;
    size_t zbytes = (size_t)(wsb - (char*)d_ws);
    unsigned short* kv_t = (unsigned short*)wsb; wsb += 2048 * 512 * 2;
    unsigned short* kv_p = (unsigned short*)wsb; wsb += 2048 * 1024 * 2;
    unsigned short* kv_c = (unsigned short*)wsb; wsb += 2048 * 2048 * 2;
    float* S_t = (float*)wsb; wsb += (size_t)4  * 64 * 2048 * 4;
    float* S_p = (float*)wsb; wsb += (size_t)8  * 64 * 2048 * 4;
    float* S_c = (float*)wsb; wsb += (size_t)16 * 64 * 2048 * 4;
    float* out = (float*)d_out;

    hipMemsetAsync(d_ws, 0, zbytes, stream);
    hipMemsetAsync(d_out, 0, (size_t)out_size, stream);   // lifts accumulate atomically

    // ---- launch 1: bundle query heads (NT, Kc=128 -> uniform 4-step waves)
    {
        WaveBatch G{}; int tot = 0; G.nd = 0;
        addw(G, tot, hs, Wq_c, bq_c, q_c, 4096, 128, 0, 1024, 32, 32, 0);
        addw(G, tot, hs, Wq_p, bq_p, q_p, 4096, 128, 0, 512,  16, 32, 0);
        addw(G, tot, hs, Wq_t, bq_t, q_t, 4096, 128, 0, 256,  8,  32, 0);
        wave_gemm<<<dim3(tot), dim3(64), 0, stream>>>(G);
    }

    // ---- launch 2: kv projections, 128x128 tile (bf16 out)
    {
        Batch128 G{}; int tot = 0; G.nd = 0;
        add128(G, tot, fib_c, Wqkv_c + 1024 * 1024, bqkv_c + 1024, kv_c, 1024, 2048, 16, 16);
        add128(G, tot, fib_p, Wqkv_p + 512 * 512,   bqkv_p + 512,  kv_p, 512,  1024, 8,  16);
        add128(G, tot, fib_t, Wqkv_t + 256 * 256,   bqkv_t + 256,  kv_t, 256,  512,  4,  16);
        gemm128<<<dim3(tot), dim3(256), 0, stream>>>(G);
    }

    // ---- launch 3: q in-proj (NT, Kc=128)
    {
        WaveBatch G{}; int tot = 0; G.nd = 0;
        addw(G, tot, q_c, Wqkv_c, bqkv_c, qp_c, 1024, 128, 0, 1024, 32, 8, 0);
        addw(G, tot, q_p, Wqkv_p, bqkv_p, qp_p, 512,  128, 0, 512,  16, 4, 0);
        addw(G, tot, q_t, Wqkv_t, bqkv_t, qp_t, 256,  128, 0, 256,  8,  2, 0);
        wave_gemm<<<dim3(tot), dim3(64), 0, stream>>>(G);
    }

    // ---- launch 4/5/6: attention
    qk_batch<<<dim3(16, 28), dim3(256), 0, stream>>>(qp_t, qp_p, qp_c, kv_t, kv_p, kv_c, S_t, S_p, S_c);
    softmax_p<<<dim3(28, 64), dim3(256), 0, stream>>>(S_t, S_p, S_c, mask);
    pv_batch<<<dim3(28, 16), dim3(64), 0, stream>>>(S_t, S_p, S_c, kv_t, kv_p, kv_c, o_t, o_p, o_c);

    // ---- launch 7: out-proj (NT, Kc=128)
    {
        WaveBatch G{}; int tot = 0; G.nd = 0;
        addw(G, tot, o_c, Wo_c, bo_c, po_c, 1024, 128, 0, 1024, 32, 8, 0);
        addw(G, tot, o_p, Wo_p, bo_p, po_p, 512,  128, 0, 512,  16, 4, 0);
        addw(G, tot, o_t, Wo_t, bo_t, po_t, 256,  128, 0, 256,  8,  2, 0);
        wave_gemm<<<dim3(tot), dim3(64), 0, stream>>>(G);
    }

    // ---- launch 8: lifts (NN, split-K 4/2/1 -> uniform 8-step waves,
    //      4608 waves = 18/CU; bias applied by kz==0 wave)
    {
        WaveBatch G{}; int tot = 0; G.nd = 0;
        for (int z = 0; z < 4; ++z)
            addw(G, tot, po_c, Wl_c + (size_t)z * 1024 * 4096, bl_c + z * 4096,
                 out + (size_t)(12 + z) * 4096, 1024, 256, 4096, 16 * 4096, 128, 4, 1);
        for (int z = 0; z < 8; ++z)
            addw(G, tot, po_p, Wl_p + (size_t)z * 512 * 4096, bl_p + z * 4096,
                 out + (size_t)(4 + z) * 4096, 512, 256, 4096, 16 * 4096, 128, 2, 1);
        for (int z = 0; z < 4; ++z)
            addw(G, tot, po_t, Wl_t + (size_t)z * 256 * 4096, bl_t + z * 4096,
                 out + (size_t)z * 4096, 256, 256, 4096, 16 * 4096, 128, 1, 1);
        wave_gemm<<<dim3(tot), dim3(64), 0, stream>>>(G);
    }

    // ---- launch 9: layernorm in place
    ln_kernel<<<dim3(1024), dim3(256), 0, stream>>>(out, ln_g, ln_b);
}

// Round 5
// 392.635 us; speedup vs baseline: 1.0093x; 1.0093x over previous
//
#include <hip/hip_runtime.h>
#include <cstdint>
#include <cstddef>

typedef __attribute__((ext_vector_type(8))) short short8;
typedef __attribute__((ext_vector_type(4))) short short4v;
typedef __attribute__((ext_vector_type(4))) float floatx4;

__device__ __forceinline__ unsigned short f2bf(float f) {
    unsigned int u = __builtin_bit_cast(unsigned int, f);
    u += 0x7fffu + ((u >> 16) & 1u);
    return (unsigned short)(u >> 16);
}
__device__ __forceinline__ short8 pack8(float4 a, float4 b) {
    short8 r;
    r[0] = (short)f2bf(a.x); r[1] = (short)f2bf(a.y);
    r[2] = (short)f2bf(a.z); r[3] = (short)f2bf(a.w);
    r[4] = (short)f2bf(b.x); r[5] = (short)f2bf(b.y);
    r[6] = (short)f2bf(b.z); r[7] = (short)f2bf(b.w);
    return r;
}
__device__ __forceinline__ short4v pack4(float4 a) {
    short4v r;
    r[0] = (short)f2bf(a.x); r[1] = (short)f2bf(a.y);
    r[2] = (short)f2bf(a.z); r[3] = (short)f2bf(a.w);
    return r;
}

// ---------------------------------------------------------------------------
// wave_gemm v2: ONE WAVE per block, tile 64(M) x 32(N), NO BARRIERS.
// Round-4 lesson: loading fragments straight from global = 64 segments per
// instruction (64 rows x 16B at 4KB stride) -> ~576 L2 transactions per
// K-step; the grid serializes on L2 request throughput (BW 1.3 TB/s, all
// pipes idle). Fix: COALESCED global loads (8 rows x 128B contiguous per
// instr) staged to LDS as bf16 — within a single wave LDS needs no
// __syncthreads (lgkmcnt ordering), so the zero-barrier property stays.
// 96 segments/step instead of 576. LDS 15.4 KB, double-buffered.
// mode 0 (NT): W f32 (N,K) row-major  (qheads / inproj / outproj)
// mode 1 (NN): W f32 (K,N), ldw=N     (lifts; B transposed on LDS store)
// Split-K via atomicAdd when nkz>1 (dest pre-zeroed); bias added at kz==0.
// ---------------------------------------------------------------------------
struct WaveG {
    const float* A; const float* W; const float* bias; float* C;
    int K, Kc, ldw, ldc, nj, nkz, mode;
};
struct WaveBatch { WaveG d[16]; int start[16]; int nd; };

__global__ __launch_bounds__(64, 4) void wave_gemm(WaveBatch wb)
{
    __shared__ __align__(16) short Abuf[2][64 * 40];
    __shared__ __align__(16) short Bbuf[2][32 * 40];

    const int bx = blockIdx.x;
    int di = 0;
#pragma unroll 1
    for (int i = 1; i < wb.nd; ++i) if (bx >= wb.start[i]) di = i;
    const WaveG g = wb.d[di];
    int local = bx - wb.start[di];
    const int j = local % g.nj;
    const int kz = local / g.nj;

    const int lane = threadIdx.x;
    const int quad = lane >> 4, l16 = lane & 15;
    const int ldr  = lane >> 3;          // load row-in-group 0..7
    const int ldc4 = (lane & 7) * 4;     // load col within 32-float row

    // global bases (step 0)
    const float* pa = g.A + (size_t)ldr * g.K + kz * g.Kc + ldc4;
    const float* pb;
    size_t pbstep;                        // per-K-step pointer advance
    size_t pbpass;                        // per-pass (8 rows) advance
    if (g.mode == 0) {                    // NT: rows are n, k contiguous
        pb = g.W + (size_t)(j * 32 + ldr) * g.K + kz * g.Kc + ldc4;
        pbstep = 32; pbpass = (size_t)8 * g.K;
    } else {                              // NN: rows are k, n contiguous
        pb = g.W + ((size_t)(kz * g.Kc) + ldr) * g.ldw + j * 32 + ldc4;
        pbstep = (size_t)32 * g.ldw; pbpass = (size_t)8 * g.ldw;
    }
    const size_t papass = (size_t)8 * g.K;

    const int steps = g.Kc >> 5;

    // staging registers (static indexing -> stays in VGPRs)
    float4 ra[8], rb[4];

#define LOADSTEP(soff) { \
    _Pragma("unroll") for (int p_ = 0; p_ < 8; ++p_) \
        ra[p_] = *(const float4*)(pa + (soff) * 32 + p_ * papass); \
    _Pragma("unroll") for (int p_ = 0; p_ < 4; ++p_) \
        rb[p_] = *(const float4*)(pb + (soff) * pbstep + p_ * pbpass); }

#define STORESTEP(buf) { \
    _Pragma("unroll") for (int p_ = 0; p_ < 8; ++p_) \
        *(short4v*)&Abuf[buf][(p_ * 8 + ldr) * 40 + ldc4] = pack4(ra[p_]); \
    if (g.mode == 0) { \
        _Pragma("unroll") for (int p_ = 0; p_ < 4; ++p_) \
            *(short4v*)&Bbuf[buf][(p_ * 8 + ldr) * 40 + ldc4] = pack4(rb[p_]); \
    } else { \
        _Pragma("unroll") for (int p_ = 0; p_ < 4; ++p_) { \
            const int krow_ = p_ * 8 + ldr; \
            Bbuf[buf][(ldc4 + 0) * 40 + krow_] = (short)f2bf(rb[p_].x); \
            Bbuf[buf][(ldc4 + 1) * 40 + krow_] = (short)f2bf(rb[p_].y); \
            Bbuf[buf][(ldc4 + 2) * 40 + krow_] = (short)f2bf(rb[p_].z); \
            Bbuf[buf][(ldc4 + 3) * 40 + krow_] = (short)f2bf(rb[p_].w); \
        } } }

    floatx4 acc[4][2] = {};

    // prologue: stage step 0, prefetch step 1 into regs
    LOADSTEP(0);
    STORESTEP(0);
    if (steps > 1) LOADSTEP(1);

    int cur = 0;
#pragma unroll 1
    for (int s = 0; s < steps; ++s) {
        short8 af[4], bfr0, bfr1;
#pragma unroll
        for (int r = 0; r < 4; ++r)
            af[r] = *(const short8*)&Abuf[cur][(r * 16 + l16) * 40 + quad * 8];
        bfr0 = *(const short8*)&Bbuf[cur][(l16) * 40 + quad * 8];
        bfr1 = *(const short8*)&Bbuf[cur][(16 + l16) * 40 + quad * 8];
#pragma unroll
        for (int r = 0; r < 4; ++r) {
            acc[r][0] = __builtin_amdgcn_mfma_f32_16x16x32_bf16(af[r], bfr0, acc[r][0], 0, 0, 0);
            acc[r][1] = __builtin_amdgcn_mfma_f32_16x16x32_bf16(af[r], bfr1, acc[r][1], 0, 0, 0);
        }
        if (s + 1 < steps) {
            STORESTEP(cur ^ 1);               // regs of step s+1 (waits vmcnt)
            if (s + 2 < steps) LOADSTEP(s + 2);
        }
        cur ^= 1;
    }

#pragma unroll
    for (int r = 0; r < 4; ++r)
#pragma unroll
        for (int c = 0; c < 2; ++c) {
            const int col = j * 32 + c * 16 + l16;
            const float bj = (kz == 0) ? g.bias[col] : 0.f;
#pragma unroll
            for (int q = 0; q < 4; ++q) {
                const int row = r * 16 + quad * 4 + q;
                const float v = acc[r][c][q] + bj;
                if (g.nkz > 1) atomicAdd(&g.C[(size_t)row * g.ldc + col], v);
                else           g.C[(size_t)row * g.ldc + col] = v;
            }
        }
#undef LOADSTEP
#undef STORESTEP
}

// ---------------------------------------------------------------------------
// gemm128: 128x128x32 tile for the big kv projections (NT, W f32 (N,K),
// bf16 out). 4 waves in 2x2, each 64x64 (acc 4x4). Both operands staged in
// LDS, double-buffered, one barrier per K-step, XOR swizzle (2-way, free).
// ---------------------------------------------------------------------------
struct Sub128 { const float* A; const float* W; const float* bias; unsigned short* C; int K, N, nj; };
struct Batch128 { Sub128 d[4]; int start[4]; int nd; };

__global__ __launch_bounds__(256) void gemm128(Batch128 gb)
{
    __shared__ short As[2][128 * 40];
    __shared__ short Bs[2][128 * 40];

    const int bx = blockIdx.x;
    int di = 0;
#pragma unroll 1
    for (int i = 1; i < gb.nd; ++i) if (bx >= gb.start[i]) di = i;
    const Sub128 g = gb.d[di];
    const int local = bx - gb.start[di];
    const int jb = local % g.nj, ib = local / g.nj;

    const int tid = threadIdx.x;
    const int w = tid >> 6, lane = tid & 63;
    const int quad = lane >> 4, l16 = lane & 15;
    const int wm = (w >> 1) * 64, wn = (w & 1) * 64;

    const int rS = tid >> 1;
    const int gi0 = (tid & 1) * 2;
    const int jsw = (rS >> 3) & 3;
    const int s1 = rS * 40 + ((gi0 ^ jsw) << 3);
    const int s2 = rS * 40 + (((gi0 + 1) ^ jsw) << 3);
    const float* pa = g.A + (size_t)(ib * 128 + rS) * g.K + (tid & 1) * 16;
    const float* pb = g.W + (size_t)(jb * 128 + rS) * g.K + (tid & 1) * 16;

    int aoff[4], boff[4];
#pragma unroll
    for (int r = 0; r < 4; ++r) {
        int rowA = wm + r * 16 + l16;
        aoff[r] = rowA * 40 + ((quad ^ ((rowA >> 3) & 3)) << 3);
        int rowB = wn + r * 16 + l16;
        boff[r] = rowB * 40 + ((quad ^ ((rowB >> 3) & 3)) << 3);
    }

    floatx4 acc[4][4] = {};
    float4 a0 = *(const float4*)pa,       a1 = *(const float4*)(pa + 4);
    float4 a2 = *(const float4*)(pa + 8), a3 = *(const float4*)(pa + 12);
    float4 b0 = *(const float4*)pb,       b1 = *(const float4*)(pb + 4);
    float4 b2 = *(const float4*)(pb + 8), b3 = *(const float4*)(pb + 12);
    *(short8*)&As[0][s1] = pack8(a0, a1);
    *(short8*)&As[0][s2] = pack8(a2, a3);
    *(short8*)&Bs[0][s1] = pack8(b0, b1);
    *(short8*)&Bs[0][s2] = pack8(b2, b3);
    if (g.K > 32) {
        pa += 32; pb += 32;
        a0 = *(const float4*)pa;       a1 = *(const float4*)(pa + 4);
        a2 = *(const float4*)(pa + 8); a3 = *(const float4*)(pa + 12);
        b0 = *(const float4*)pb;       b1 = *(const float4*)(pb + 4);
        b2 = *(const float4*)(pb + 8); b3 = *(const float4*)(pb + 12);
    }
    int cur = 0;
#pragma unroll 1
    for (int k0 = 0; k0 < g.K; k0 += 32) {
        __syncthreads();
        short8 af[4], bf[4];
#pragma unroll
        for (int r = 0; r < 4; ++r) {
            af[r] = *(const short8*)&As[cur][aoff[r]];
            bf[r] = *(const short8*)&Bs[cur][boff[r]];
        }
#pragma unroll
        for (int r = 0; r < 4; ++r)
#pragma unroll
            for (int c = 0; c < 4; ++c)
                acc[r][c] = __builtin_amdgcn_mfma_f32_16x16x32_bf16(af[r], bf[c], acc[r][c], 0, 0, 0);
        if (k0 + 32 < g.K) {
            short* An = As[cur ^ 1]; short* Bn = Bs[cur ^ 1];
            *(short8*)&An[s1] = pack8(a0, a1);
            *(short8*)&An[s2] = pack8(a2, a3);
            *(short8*)&Bn[s1] = pack8(b0, b1);
            *(short8*)&Bn[s2] = pack8(b2, b3);
            if (k0 + 64 < g.K) {
                pa += 32; pb += 32;
                a0 = *(const float4*)pa;       a1 = *(const float4*)(pa + 4);
                a2 = *(const float4*)(pa + 8); a3 = *(const float4*)(pa + 12);
                b0 = *(const float4*)pb;       b1 = *(const float4*)(pb + 4);
                b2 = *(const float4*)(pb + 8); b3 = *(const float4*)(pb + 12);
            }
        }
        cur ^= 1;
    }

#pragma unroll
    for (int r = 0; r < 4; ++r)
#pragma unroll
        for (int c = 0; c < 4; ++c) {
            const int col = jb * 128 + wn + c * 16 + l16;
            const float bj = g.bias[col];
#pragma unroll
            for (int q = 0; q < 4; ++q) {
                const int row = ib * 128 + wm + r * 16 + quad * 4 + q;
                g.C[(size_t)row * g.N + col] = f2bf(acc[r][c][q] + bj);
            }
        }
}

// ---------------------------------------------------------------------------
// qk_batch: S(64b x 128m tile) = 0.125 * Q_h @ K_h^T, all 28 heads batched.
// ---------------------------------------------------------------------------
__global__ __launch_bounds__(256) void qk_batch(
    const float* __restrict__ qp_t, const float* __restrict__ qp_p, const float* __restrict__ qp_c,
    const unsigned short* __restrict__ kv_t, const unsigned short* __restrict__ kv_p, const unsigned short* __restrict__ kv_c,
    float* __restrict__ S_t, float* __restrict__ S_p, float* __restrict__ S_c)
{
    __shared__ short As[64 * 72];
    __shared__ short Bs[128 * 72];
    const int hy = blockIdx.y;
    const float* qp; const unsigned short* kv; float* S; int d, h;
    if (hy < 4)       { qp = qp_t; kv = kv_t; S = S_t; d = 256;  h = hy; }
    else if (hy < 12) { qp = qp_p; kv = kv_p; S = S_p; d = 512;  h = hy - 4; }
    else              { qp = qp_c; kv = kv_c; S = S_c; d = 1024; h = hy - 12; }

    const int j0 = blockIdx.x * 128;
    const int tid = threadIdx.x;
    const int w = tid >> 6, lane = tid & 63;
    const int quad = lane >> 4, l16 = lane & 15;
    const int noff = w * 32;
    const int twoD = 2 * d;

    {
        const int b = tid >> 2, kc = (tid & 3) * 16;
        const float* ga = qp + (size_t)b * d + h * 64 + kc;
        float4 a0 = *(const float4*)(ga + 0), a1 = *(const float4*)(ga + 4);
        float4 a2 = *(const float4*)(ga + 8), a3 = *(const float4*)(ga + 12);
        *(short8*)&As[b * 72 + kc + 0] = pack8(a0, a1);
        *(short8*)&As[b * 72 + kc + 8] = pack8(a2, a3);
    }
    {
        const int m = tid >> 1, hf = (tid & 1) * 32;
        const unsigned short* gb = kv + (size_t)(j0 + m) * twoD + h * 64 + hf;
        uint4 b0 = *(const uint4*)(gb + 0),  b1 = *(const uint4*)(gb + 8);
        uint4 b2 = *(const uint4*)(gb + 16), b3 = *(const uint4*)(gb + 24);
        *(uint4*)&Bs[m * 72 + hf + 0]  = b0;
        *(uint4*)&Bs[m * 72 + hf + 8]  = b1;
        *(uint4*)&Bs[m * 72 + hf + 16] = b2;
        *(uint4*)&Bs[m * 72 + hf + 24] = b3;
    }
    __syncthreads();

    floatx4 acc[4][2] = {};
#pragma unroll
    for (int k0 = 0; k0 < 64; k0 += 32) {
        short8 af[4], bfr[2];
#pragma unroll
        for (int r = 0; r < 4; ++r)
            af[r] = *(const short8*)&As[(r * 16 + l16) * 72 + k0 + quad * 8];
#pragma unroll
        for (int c = 0; c < 2; ++c)
            bfr[c] = *(const short8*)&Bs[(noff + c * 16 + l16) * 72 + k0 + quad * 8];
#pragma unroll
        for (int r = 0; r < 4; ++r)
#pragma unroll
            for (int c = 0; c < 2; ++c)
                acc[r][c] = __builtin_amdgcn_mfma_f32_16x16x32_bf16(af[r], bfr[c], acc[r][c], 0, 0, 0);
    }
#pragma unroll
    for (int r = 0; r < 4; ++r)
#pragma unroll
        for (int c = 0; c < 2; ++c) {
            int col = j0 + noff + c * 16 + l16;
#pragma unroll
            for (int q = 0; q < 4; ++q) {
                int row = r * 16 + quad * 4 + q;
                S[((size_t)h * 64 + row) * 2048 + col] = acc[r][c][q] * 0.125f;
            }
        }
}

// ---------------------------------------------------------------------------
// softmax_p: per (head, b): softmax over the S row, written back IN PLACE.
// ---------------------------------------------------------------------------
__global__ __launch_bounds__(256) void softmax_p(
    float* __restrict__ S_t, float* __restrict__ S_p, float* __restrict__ S_c,
    const uint8_t* __restrict__ mask)
{
    const int hy = blockIdx.x, b = blockIdx.y;
    float* S; int h;
    if (hy < 4)       { S = S_t; h = hy; }
    else if (hy < 12) { S = S_p; h = hy - 4; }
    else              { S = S_c; h = hy - 12; }

    const int tid = threadIdx.x;
    __shared__ __align__(16) float sc[2048];
    __shared__ float red[4];
    __shared__ float s_max, s_sum;

    float* Sr = S + ((size_t)h * 64 + b) * 2048;
    const uint8_t* mr = mask + (size_t)b * 2048;

    float lmax = -1e30f;
    for (int m = tid; m < 2048; m += 256) {
        float s = Sr[m];
        if (mr[m]) s = -1e9f;
        sc[m] = s;
        lmax = fmaxf(lmax, s);
    }
#pragma unroll
    for (int off = 32; off; off >>= 1) lmax = fmaxf(lmax, __shfl_down(lmax, off));
    if ((tid & 63) == 0) red[tid >> 6] = lmax;
    __syncthreads();
    if (tid == 0) s_max = fmaxf(fmaxf(red[0], red[1]), fmaxf(red[2], red[3]));
    __syncthreads();
    const float mx = s_max;

    float lsum = 0.f;
    for (int m = tid; m < 2048; m += 256) {
        float e = __expf(sc[m] - mx);
        sc[m] = e;
        lsum += e;
    }
#pragma unroll
    for (int off = 32; off; off >>= 1) lsum += __shfl_down(lsum, off);
    if ((tid & 63) == 0) red[tid >> 6] = lsum;
    __syncthreads();
    if (tid == 0) s_sum = red[0] + red[1] + red[2] + red[3];
    __syncthreads();
    const float inv = 1.f / s_sum;

    for (int m = tid; m < 2048; m += 256) Sr[m] = sc[m] * inv;
}

// ---------------------------------------------------------------------------
// pv_batch: O_h = P_h(64x2048) @ V_h(2048x64), one wave per (head, k-chunk
// of 128). Grid (28, 16). atomicAdd into zeroed o_*.
// ---------------------------------------------------------------------------
__global__ __launch_bounds__(64) void pv_batch(
    const float* __restrict__ P_t, const float* __restrict__ P_p, const float* __restrict__ P_c,
    const unsigned short* __restrict__ kv_t, const unsigned short* __restrict__ kv_p, const unsigned short* __restrict__ kv_c,
    float* __restrict__ o_t, float* __restrict__ o_p, float* __restrict__ o_c)
{
    const int hy = blockIdx.x, kz = blockIdx.y;
    const float* P; const unsigned short* kv; float* o; int d, h;
    if (hy < 4)       { P = P_t; kv = kv_t; o = o_t; d = 256;  h = hy; }
    else if (hy < 12) { P = P_p; kv = kv_p; o = o_p; d = 512;  h = hy - 4; }
    else              { P = P_c; kv = kv_c; o = o_c; d = 1024; h = hy - 12; }

    const int lane = threadIdx.x;
    const int quad = lane >> 4, l16 = lane & 15;
    const int twoD = 2 * d;

    const float* pa[4];
#pragma unroll
    for (int r = 0; r < 4; ++r)
        pa[r] = P + ((size_t)h * 64 + r * 16 + l16) * 2048 + kz * 128 + quad * 8;
    const unsigned short* pb = kv + (size_t)(kz * 128 + quad * 8) * twoD + d + h * 64 + l16;

    floatx4 acc[4][4] = {};
#pragma unroll 1
    for (int s = 0; s < 4; ++s) {
        short8 af[4];
#pragma unroll
        for (int r = 0; r < 4; ++r) {
            float4 a0 = *(const float4*)pa[r], a1 = *(const float4*)(pa[r] + 4);
            af[r] = pack8(a0, a1);
            pa[r] += 32;
        }
        short8 bf[4];
#pragma unroll
        for (int c = 0; c < 4; ++c)
#pragma unroll
            for (int i = 0; i < 8; ++i)
                bf[c][i] = (short)pb[(size_t)i * twoD + c * 16];
        pb += (size_t)32 * twoD;
#pragma unroll
        for (int r = 0; r < 4; ++r)
#pragma unroll
            for (int c = 0; c < 4; ++c)
                acc[r][c] = __builtin_amdgcn_mfma_f32_16x16x32_bf16(af[r], bf[c], acc[r][c], 0, 0, 0);
    }
#pragma unroll
    for (int r = 0; r < 4; ++r)
#pragma unroll
        for (int c = 0; c < 4; ++c)
#pragma unroll
            for (int q = 0; q < 4; ++q) {
                const int row = r * 16 + quad * 4 + q;
                atomicAdd(&o[(size_t)row * d + h * 64 + c * 16 + l16], acc[r][c][q]);
            }
}

// ---------------------------------------------------------------------------
__global__ __launch_bounds__(256) void ln_kernel(
    float* __restrict__ x, const float* __restrict__ g, const float* __restrict__ bb)
{
    const int row = blockIdx.x;
    float* xr = x + (size_t)row * 4096;
    const int tid = threadIdx.x;
    float v[16];
    float sum = 0.f, sumsq = 0.f;
#pragma unroll
    for (int i = 0; i < 16; ++i) {
        v[i] = xr[tid + i * 256];
        sum += v[i];
        sumsq += v[i] * v[i];
    }
    __shared__ float rs[4], rq[4];
#pragma unroll
    for (int off = 32; off; off >>= 1) {
        sum += __shfl_down(sum, off);
        sumsq += __shfl_down(sumsq, off);
    }
    if ((tid & 63) == 0) { rs[tid >> 6] = sum; rq[tid >> 6] = sumsq; }
    __syncthreads();
    const float ts = rs[0] + rs[1] + rs[2] + rs[3];
    const float tq = rq[0] + rq[1] + rq[2] + rq[3];
    const float mu = ts * (1.f / 4096.f);
    const float var = tq * (1.f / 4096.f) - mu * mu;
    const float r = rsqrtf(var + 1e-5f);
#pragma unroll
    for (int i = 0; i < 16; ++i) {
        int e = tid + i * 256;
        xr[e] = (v[i] - mu) * r * g[e] + bb[e];
    }
}

// ---------------------------------------------------------------------------
static void addw(WaveBatch& G, int& tot,
                 const float* A, const float* W, const float* bias, float* C,
                 int K, int Kc, int ldw, int ldc, int nj, int nkz, int mode)
{
    WaveG& s = G.d[G.nd];
    s.A = A; s.W = W; s.bias = bias; s.C = C;
    s.K = K; s.Kc = Kc; s.ldw = ldw; s.ldc = ldc; s.nj = nj; s.nkz = nkz; s.mode = mode;
    G.start[G.nd] = tot;
    tot += nj * nkz;
    G.nd++;
}
static void add128(Batch128& G, int& tot,
                   const float* A, const float* W, const float* bias, unsigned short* C,
                   int K, int N, int nj, int ni)
{
    Sub128& s = G.d[G.nd];
    s.A = A; s.W = W; s.bias = bias; s.C = C; s.K = K; s.N = N; s.nj = nj;
    G.start[G.nd] = tot;
    tot += nj * ni;
    G.nd++;
}

extern "C" void kernel_launch(void* const* d_in, const int* in_sizes, int n_in,
                              void* d_out, int out_size, void* d_ws, size_t ws_size,
                              hipStream_t stream)
{
    const float*   hs     = (const float*)d_in[0];
    const float*   fib_t  = (const float*)d_in[1];
    const float*   fib_p  = (const float*)d_in[2];
    const float*   fib_c  = (const float*)d_in[3];
    const uint8_t* mask   = (const uint8_t*)d_in[4];
    const float* Wq_t   = (const float*)d_in[5];  const float* bq_t   = (const float*)d_in[6];
    const float* Wq_p   = (const float*)d_in[7];  const float* bq_p   = (const float*)d_in[8];
    const float* Wq_c   = (const float*)d_in[9];  const float* bq_c   = (const float*)d_in[10];
    const float* Wqkv_t = (const float*)d_in[11]; const float* bqkv_t = (const float*)d_in[12];
    const float* Wo_t   = (const float*)d_in[13]; const float* bo_t   = (const float*)d_in[14];
    const float* Wqkv_p = (const float*)d_in[15]; const float* bqkv_p = (const float*)d_in[16];
    const float* Wo_p   = (const float*)d_in[17]; const float* bo_p   = (const float*)d_in[18];
    const float* Wqkv_c = (const float*)d_in[19]; const float* bqkv_c = (const float*)d_in[20];
    const float* Wo_c   = (const float*)d_in[21]; const float* bo_c   = (const float*)d_in[22];
    const float* Wl_t   = (const float*)d_in[23]; const float* bl_t   = (const float*)d_in[24];
    const float* Wl_p   = (const float*)d_in[25]; const float* bl_p   = (const float*)d_in[26];
    const float* Wl_c   = (const float*)d_in[27]; const float* bl_c   = (const float*)d_in[28];
    const float* ln_g   = (const float*)d_in[29]; const float* ln_b   = (const float*)d_in[30];

    char* wsb = (char*)d_ws;
    // zeroed region: split-K atomic destinations
    float* q_t  = (float*)wsb; wsb += 64 * 256 * 4;
    float* q_p  = (float*)wsb; wsb += 64 * 512 * 4;
    float* q_c  = (float*)wsb; wsb += 64 * 1024 * 4;
    float* qp_t = (float*)wsb; wsb += 64 * 256 * 4;
    float* qp_p = (float*)wsb; wsb += 64 * 512 * 4;
    float* qp_c = (float*)wsb; wsb += 64 * 1024 * 4;
    float* po_t = (float*)wsb; wsb += 64 * 256 * 4;
    float* po_p = (float*)wsb; wsb += 64 * 512 * 4;
    float* po_c = (float*)wsb; wsb += 64 * 1024 * 4;
    float* o_t  = (float*)wsb; wsb += 64 * 256 * 4;
    float* o_p  = (float*)wsb; wsb += 64 * 512 * 4;
    float* o_c  = (float*)wsb; wsb += 64 * 1024 * 4;
    size_t zbytes = (size_t)(wsb - (char*)d_ws);
    unsigned short* kv_t = (unsigned short*)wsb; wsb += 2048 * 512 * 2;
    unsigned short* kv_p = (unsigned short*)wsb; wsb += 2048 * 1024 * 2;
    unsigned short* kv_c = (unsigned short*)wsb; wsb += 2048 * 2048 * 2;
    float* S_t = (float*)wsb; wsb += (size_t)4  * 64 * 2048 * 4;
    float* S_p = (float*)wsb; wsb += (size_t)8  * 64 * 2048 * 4;
    float* S_c = (float*)wsb; wsb += (size_t)16 * 64 * 2048 * 4;
    float* out = (float*)d_out;

    hipMemsetAsync(d_ws, 0, zbytes, stream);
    hipMemsetAsync(d_out, 0, (size_t)out_size, stream);   // lifts accumulate atomically

    // ---- launch 1: bundle query heads (NT, Kc=128 -> uniform 4-step waves)
    {
        WaveBatch G{}; int tot = 0; G.nd = 0;
        addw(G, tot, hs, Wq_c, bq_c, q_c, 4096, 128, 0, 1024, 32, 32, 0);
        addw(G, tot, hs, Wq_p, bq_p, q_p, 4096, 128, 0, 512,  16, 32, 0);
        addw(G, tot, hs, Wq_t, bq_t, q_t, 4096, 128, 0, 256,  8,  32, 0);
        wave_gemm<<<dim3(tot), dim3(64), 0, stream>>>(G);
    }

    // ---- launch 2: kv projections, 128x128 tile (bf16 out)
    {
        Batch128 G{}; int tot = 0; G.nd = 0;
        add128(G, tot, fib_c, Wqkv_c + 1024 * 1024, bqkv_c + 1024, kv_c, 1024, 2048, 16, 16);
        add128(G, tot, fib_p, Wqkv_p + 512 * 512,   bqkv_p + 512,  kv_p, 512,  1024, 8,  16);
        add128(G, tot, fib_t, Wqkv_t + 256 * 256,   bqkv_t + 256,  kv_t, 256,  512,  4,  16);
        gemm128<<<dim3(tot), dim3(256), 0, stream>>>(G);
    }

    // ---- launch 3: q in-proj (NT, Kc=128)
    {
        WaveBatch G{}; int tot = 0; G.nd = 0;
        addw(G, tot, q_c, Wqkv_c, bqkv_c, qp_c, 1024, 128, 0, 1024, 32, 8, 0);
        addw(G, tot, q_p, Wqkv_p, bqkv_p, qp_p, 512,  128, 0, 512,  16, 4, 0);
        addw(G, tot, q_t, Wqkv_t, bqkv_t, qp_t, 256,  128, 0, 256,  8,  2, 0);
        wave_gemm<<<dim3(tot), dim3(64), 0, stream>>>(G);
    }

    // ---- launch 4/5/6: attention
    qk_batch<<<dim3(16, 28), dim3(256), 0, stream>>>(qp_t, qp_p, qp_c, kv_t, kv_p, kv_c, S_t, S_p, S_c);
    softmax_p<<<dim3(28, 64), dim3(256), 0, stream>>>(S_t, S_p, S_c, mask);
    pv_batch<<<dim3(28, 16), dim3(64), 0, stream>>>(S_t, S_p, S_c, kv_t, kv_p, kv_c, o_t, o_p, o_c);

    // ---- launch 7: out-proj (NT, Kc=128)
    {
        WaveBatch G{}; int tot = 0; G.nd = 0;
        addw(G, tot, o_c, Wo_c, bo_c, po_c, 1024, 128, 0, 1024, 32, 8, 0);
        addw(G, tot, o_p, Wo_p, bo_p, po_p, 512,  128, 0, 512,  16, 4, 0);
        addw(G, tot, o_t, Wo_t, bo_t, po_t, 256,  128, 0, 256,  8,  2, 0);
        wave_gemm<<<dim3(tot), dim3(64), 0, stream>>>(G);
    }

    // ---- launch 8: lifts (NN, split-K 4/2/1 -> uniform 8-step waves)
    {
        WaveBatch G{}; int tot = 0; G.nd = 0;
        for (int z = 0; z < 4; ++z)
            addw(G, tot, po_c, Wl_c + (size_t)z * 1024 * 4096, bl_c + z * 4096,
                 out + (size_t)(12 + z) * 4096, 1024, 256, 4096, 16 * 4096, 128, 4, 1);
        for (int z = 0; z < 8; ++z)
            addw(G, tot, po_p, Wl_p + (size_t)z * 512 * 4096, bl_p + z * 4096,
                 out + (size_t)(4 + z) * 4096, 512, 256, 4096, 16 * 4096, 128, 2, 1);
        for (int z = 0; z < 4; ++z)
            addw(G, tot, po_t, Wl_t + (size_t)z * 256 * 4096, bl_t + z * 4096,
                 out + (size_t)z * 4096, 256, 256, 4096, 16 * 4096, 128, 1, 1);
        wave_gemm<<<dim3(tot), dim3(64), 0, stream>>>(G);
    }

    // ---- launch 9: layernorm in place
    ln_kernel<<<dim3(1024), dim3(256), 0, stream>>>(out, ln_g, ln_b);
}